// Round 1
// baseline (88.642 us; speedup 1.0000x reference)
//
#include <hip/hip_runtime.h>
#include <math.h>

#define TPB 256
#define JCHUNK 1024

// Stage 1: each block handles 256 i's x one 1024-wide j-chunk.
// Full (ordered-pair) sum; symmetry makes total/count identical to the
// triangular reference. Masked/equal targets are killed via NaN sentinel.
__global__ __launch_bounds__(TPB) void mrl_partial(
    const float* __restrict__ p, const float* __restrict__ t,
    const int* __restrict__ m, int B,
    float* __restrict__ blk_sum, float* __restrict__ blk_cnt)
{
    __shared__ float sp[JCHUNK];
    __shared__ float st[JCHUNK];   // NaN where masked / OOB

    const int i  = blockIdx.x * TPB + threadIdx.x;
    const int j0 = blockIdx.y * JCHUNK;

    for (int k = threadIdx.x; k < JCHUNK; k += TPB) {
        int j = j0 + k;
        if (j < B) {
            sp[k] = p[j];
            st[k] = m[j] ? t[j] : __builtin_nanf("");
        } else {
            sp[k] = 0.0f;
            st[k] = __builtin_nanf("");
        }
    }
    __syncthreads();

    float pi = 0.0f, ti = __builtin_nanf("");
    if (i < B) {
        pi = p[i];
        ti = m[i] ? t[i] : __builtin_nanf("");
    }

    float acc = 0.0f;
    int   cnt = 0;
    const int jmax = (B - j0) < JCHUNK ? (B - j0) : JCHUNK;
    #pragma unroll 8
    for (int k = 0; k < jmax; ++k) {
        float dt = ti - st[k];
        float dp = pi - sp[k];
        bool  v  = fabsf(dt) >= 1e-6f;            // false on NaN -> masked out
        float s  = (dt > 0.0f) ? 1.0f : -1.0f;    // sign well-defined when valid
        float h  = fmaxf(0.0f, fmaf(-s, dp, 0.1f));
        if (v) { acc += h; cnt++; }
    }

    // block reduction: wave shuffle then cross-wave via LDS
    float c = (float)cnt;                          // <= 1024/thread, exact
    #pragma unroll
    for (int off = 32; off > 0; off >>= 1) {
        acc += __shfl_down(acc, off, 64);
        c   += __shfl_down(c,   off, 64);
    }
    __shared__ float wsum[TPB / 64];
    __shared__ float wcnt[TPB / 64];
    const int lane = threadIdx.x & 63;
    const int wid  = threadIdx.x >> 6;
    if (lane == 0) { wsum[wid] = acc; wcnt[wid] = c; }
    __syncthreads();
    if (threadIdx.x == 0) {
        float a = 0.0f, cc = 0.0f;
        #pragma unroll
        for (int w = 0; w < TPB / 64; ++w) { a += wsum[w]; cc += wcnt[w]; }
        const int blk = blockIdx.y * gridDim.x + blockIdx.x;
        blk_sum[blk] = a;
        blk_cnt[blk] = cc;
    }
}

// Stage 2: single block reduces all per-block partials in double and divides.
__global__ __launch_bounds__(256) void mrl_final(
    const float* __restrict__ blk_sum, const float* __restrict__ blk_cnt,
    int nblk, float* __restrict__ out)
{
    double a = 0.0, c = 0.0;
    for (int k = threadIdx.x; k < nblk; k += 256) {
        a += (double)blk_sum[k];
        c += (double)blk_cnt[k];
    }
    #pragma unroll
    for (int off = 32; off > 0; off >>= 1) {
        a += __shfl_down(a, off, 64);
        c += __shfl_down(c, off, 64);
    }
    __shared__ double sa[4];
    __shared__ double sc[4];
    const int lane = threadIdx.x & 63;
    const int wid  = threadIdx.x >> 6;
    if (lane == 0) { sa[wid] = a; sc[wid] = c; }
    __syncthreads();
    if (threadIdx.x == 0) {
        double A = 0.0, C = 0.0;
        #pragma unroll
        for (int w = 0; w < 4; ++w) { A += sa[w]; C += sc[w]; }
        out[0] = (C > 0.0) ? (float)(A / C) : 0.0f;
    }
}

extern "C" void kernel_launch(void* const* d_in, const int* in_sizes, int n_in,
                              void* d_out, int out_size, void* d_ws, size_t ws_size,
                              hipStream_t stream)
{
    const float* p = (const float*)d_in[0];
    const float* t = (const float*)d_in[1];
    const int*   m = (const int*)d_in[2];
    const int B = in_sizes[0];

    const int iblocks = (B + TPB - 1) / TPB;
    const int jchunks = (B + JCHUNK - 1) / JCHUNK;
    const int nblk = iblocks * jchunks;

    float* blk_sum = (float*)d_ws;
    float* blk_cnt = blk_sum + nblk;

    dim3 grid(iblocks, jchunks);
    mrl_partial<<<grid, TPB, 0, stream>>>(p, t, m, B, blk_sum, blk_cnt);
    mrl_final<<<1, 256, 0, stream>>>(blk_sum, blk_cnt, nblk, (float*)d_out);
}

// Round 2
// 75.481 us; speedup vs baseline: 1.1744x; 1.1744x over previous
//
#include <hip/hip_runtime.h>
#include <math.h>

#define TPB 256
#define JCHUNK 128

// Pairwise MarginRankingLoss. h(i,j) = max(0, -sign(t_i-t_j)*(p_i-p_j) + 0.1)
// is symmetric under i<->j, so we compute only j>i pairs (triangular) and
// take sum/count directly. Masked / |dt|<eps / OOB pairs are killed via a
// NaN sentinel in the staged target value (any compare with NaN is false).
//
// Grid: x = i-blocks (TPB i's per block), y = j-chunks (JCHUNK j's staged in
// LDS). Blocks entirely at/below the diagonal exit early (write zero
// partials). Only diagonal-straddling blocks pay the j>i predicate.
__global__ __launch_bounds__(TPB) void mrl_partial(
    const float* __restrict__ p, const float* __restrict__ t,
    const int* __restrict__ m, int B,
    float* __restrict__ blk_sum, float* __restrict__ blk_cnt)
{
    const int i0  = blockIdx.x * TPB;
    const int j0  = blockIdx.y * JCHUNK;
    const int blk = blockIdx.y * gridDim.x + blockIdx.x;

    // no pair (i,j) with j>i exists in this tile -> skip
    if (j0 + JCHUNK - 1 <= i0) {
        if (threadIdx.x == 0) { blk_sum[blk] = 0.0f; blk_cnt[blk] = 0.0f; }
        return;
    }

    __shared__ float sp[JCHUNK];
    __shared__ float st[JCHUNK];   // NaN where masked / OOB

    if (threadIdx.x < JCHUNK) {
        const int j = j0 + threadIdx.x;
        const bool ok = (j < B);
        sp[threadIdx.x] = ok ? p[j] : 0.0f;
        st[threadIdx.x] = (ok && m[j]) ? t[j] : __builtin_nanf("");
    }
    __syncthreads();

    const int i = i0 + threadIdx.x;
    float pi = 0.0f, ti = __builtin_nanf("");
    if (i < B) {
        pi = p[i];
        ti = m[i] ? t[i] : __builtin_nanf("");
    }

    float acc = 0.0f, cnt = 0.0f;
    const bool diag = (j0 < i0 + TPB);   // tile straddles the diagonal

    if (!diag) {
        // entirely above diagonal: every j > every i, no predicate needed
        #pragma unroll 8
        for (int k = 0; k < JCHUNK; ++k) {
            const float dt = ti - st[k];
            const float q  = sp[k] - pi;              // q = -(p_i - p_j)
            const bool  v  = fabsf(dt) >= 1e-6f;      // false on NaN
            float h = (dt > 0.0f) ? (q + 0.1f) : (0.1f - q);
            h = fmaxf(h, 0.0f);
            if (v) { acc += h; cnt += 1.0f; }
        }
    } else {
        #pragma unroll 8
        for (int k = 0; k < JCHUNK; ++k) {
            const int   j  = j0 + k;
            const float dt = ti - st[k];
            const float q  = sp[k] - pi;
            const bool  v  = (fabsf(dt) >= 1e-6f) && (j > i);
            float h = (dt > 0.0f) ? (q + 0.1f) : (0.1f - q);
            h = fmaxf(h, 0.0f);
            if (v) { acc += h; cnt += 1.0f; }
        }
    }

    // block reduction: wave shuffle then cross-wave via LDS
    #pragma unroll
    for (int off = 32; off > 0; off >>= 1) {
        acc += __shfl_down(acc, off, 64);
        cnt += __shfl_down(cnt, off, 64);
    }
    __shared__ float wsum[TPB / 64];
    __shared__ float wcnt[TPB / 64];
    const int lane = threadIdx.x & 63;
    const int wid  = threadIdx.x >> 6;
    if (lane == 0) { wsum[wid] = acc; wcnt[wid] = cnt; }
    __syncthreads();
    if (threadIdx.x == 0) {
        float a = 0.0f, c = 0.0f;
        #pragma unroll
        for (int w = 0; w < TPB / 64; ++w) { a += wsum[w]; c += wcnt[w]; }
        blk_sum[blk] = a;
        blk_cnt[blk] = c;
    }
}

// Stage 2: single block reduces all per-block partials in double and divides.
__global__ __launch_bounds__(256) void mrl_final(
    const float* __restrict__ blk_sum, const float* __restrict__ blk_cnt,
    int nblk, float* __restrict__ out)
{
    double a = 0.0, c = 0.0;
    for (int k = threadIdx.x; k < nblk; k += 256) {
        a += (double)blk_sum[k];
        c += (double)blk_cnt[k];
    }
    #pragma unroll
    for (int off = 32; off > 0; off >>= 1) {
        a += __shfl_down(a, off, 64);
        c += __shfl_down(c, off, 64);
    }
    __shared__ double sa[4];
    __shared__ double sc[4];
    const int lane = threadIdx.x & 63;
    const int wid  = threadIdx.x >> 6;
    if (lane == 0) { sa[wid] = a; sc[wid] = c; }
    __syncthreads();
    if (threadIdx.x == 0) {
        double A = 0.0, C = 0.0;
        #pragma unroll
        for (int w = 0; w < 4; ++w) { A += sa[w]; C += sc[w]; }
        out[0] = (C > 0.0) ? (float)(A / C) : 0.0f;
    }
}

extern "C" void kernel_launch(void* const* d_in, const int* in_sizes, int n_in,
                              void* d_out, int out_size, void* d_ws, size_t ws_size,
                              hipStream_t stream)
{
    const float* p = (const float*)d_in[0];
    const float* t = (const float*)d_in[1];
    const int*   m = (const int*)d_in[2];
    const int B = in_sizes[0];

    const int iblocks = (B + TPB - 1) / TPB;
    const int jchunks = (B + JCHUNK - 1) / JCHUNK;
    const int nblk = iblocks * jchunks;

    float* blk_sum = (float*)d_ws;
    float* blk_cnt = blk_sum + nblk;

    dim3 grid(iblocks, jchunks);
    mrl_partial<<<grid, TPB, 0, stream>>>(p, t, m, B, blk_sum, blk_cnt);
    mrl_final<<<1, 256, 0, stream>>>(blk_sum, blk_cnt, nblk, (float*)d_out);
}